// Round 8
// baseline (405.301 us; speedup 1.0000x reference)
//
#include <hip/hip_runtime.h>
#include <math.h>

#define N_NODES 50000
#define N_EDGES 800000
#define E_DIM   5
#define N_G     128
#define N_ACT   8
#define SBLK    512
#define SNB     ((N_NODES + SBLK - 1) / SBLK)   // 98

// ---------------- once-per-call setup ----------------

// block 0: weff (t in [160,190)) + gstart (t in [0,129)); blocks 1..: hist
__global__ __launch_bounds__(256) void setup_kernel(
    const int* __restrict__ ei, const int* __restrict__ batch,
    const float* __restrict__ We1, const float* __restrict__ ae1,
    const float* __restrict__ We2, const float* __restrict__ ae2,
    const float* __restrict__ We3, const float* __restrict__ ae3,
    float* __restrict__ weff, int* __restrict__ gstart, int* __restrict__ hist) {
    int bid = blockIdx.x, tid = threadIdx.x;
    if (bid == 0) {
        if (tid <= N_G) {  // group boundaries in sorted batch
            int g = tid, lo = 0, hi = N_NODES;
            while (lo < hi) { int mid = (lo + hi) >> 1; if (batch[mid] < g) lo = mid + 1; else hi = mid; }
            gstart[g] = lo;
        }
        int t = tid - 160;
        if (t >= 0 && t < 30) {  // weff[l*10 + d*2 + h] = sum_c We_l[d, h*32+c]*ae_l[h,c]
            int l = t / 10, r = t % 10, d = r >> 1, h = r & 1;
            const float* We = (l == 0) ? We1 : (l == 1) ? We2 : We3;
            const float* ae = (l == 0) ? ae1 : (l == 1) ? ae2 : ae3;
            float s = 0.f;
            for (int c = 0; c < 32; ++c) s += We[d * 64 + h * 32 + c] * ae[h * 32 + c];
            weff[l * 10 + d * 2 + h] = s;
        }
        return;
    }
    int k = (bid - 1) * 256 + tid;
    if (k < N_EDGES) atomicAdd(&hist[ei[N_EDGES + k]], 1);
}

__device__ __forceinline__ int wave_incl_scan(int v, int lane) {
    #pragma unroll
    for (int off = 1; off < 64; off <<= 1) {
        int n = __shfl_up(v, off);
        if (lane >= off) v += n;
    }
    return v;
}

__global__ __launch_bounds__(SBLK) void scan_bsum_kernel(const int* __restrict__ hist,
                                                         int* __restrict__ bsum) {
    int i = blockIdx.x * SBLK + threadIdx.x;
    int v = (i < N_NODES) ? hist[i] : 0;
    __shared__ int sm[SBLK / 64];
    int lane = threadIdx.x & 63, w = threadIdx.x >> 6;
    #pragma unroll
    for (int o = 32; o; o >>= 1) v += __shfl_xor(v, o);
    if (lane == 0) sm[w] = v;
    __syncthreads();
    if (threadIdx.x == 0) {
        int s = 0;
        #pragma unroll
        for (int k = 0; k < SBLK / 64; ++k) s += sm[k];
        bsum[blockIdx.x] = s;
    }
}

// rowptr scan; each block derives its own offset from bsum (<= 97 partials)
__global__ __launch_bounds__(SBLK) void scan_rowptr_kernel(const int* __restrict__ hist,
                                                           const int* __restrict__ bsum,
                                                           int* __restrict__ rowptr) {
    __shared__ int s_boffs;
    __shared__ int wtot[SBLK / 64];
    int bid = blockIdx.x;
    if (threadIdx.x < 64) {
        int v = 0;
        for (int i = threadIdx.x; i < bid; i += 64) v += bsum[i];
        #pragma unroll
        for (int o = 32; o; o >>= 1) v += __shfl_xor(v, o);
        if (threadIdx.x == 0) s_boffs = v;
    }
    int i = bid * SBLK + threadIdx.x;
    int v = (i < N_NODES) ? hist[i] : 0;
    int lane = threadIdx.x & 63, w = threadIdx.x >> 6;
    int inc = wave_incl_scan(v, lane);
    if (lane == 63) wtot[w] = inc;
    __syncthreads();
    int woff = 0;
    for (int k = 0; k < w; ++k) woff += wtot[k];
    int excl = s_boffs + woff + inc - v;
    if (i < N_NODES) rowptr[i] = excl;
    if (i == N_NODES - 1) rowptr[N_NODES] = excl + v;
}

// phase A: compute records in EDGE order (coalesced 32B writes); scatter only 4B iperm
// recE[k*8 + {0..5}] = e . weff_{l0,l1,l2}, [6]=src bits, [7]=pad
__global__ void scatterA_kernel(const int* __restrict__ ei, const float* __restrict__ ea,
                                const float* __restrict__ weff,
                                const int* __restrict__ rowptr, int* __restrict__ cur,
                                float* __restrict__ recE, int* __restrict__ iperm) {
    int k = blockIdx.x * blockDim.x + threadIdx.x;
    if (k >= N_EDGES) return;
    int s = ei[k], d = ei[N_EDGES + k];
    const float* ep = ea + (size_t)k * E_DIM;
    float e[5];
    #pragma unroll
    for (int j = 0; j < 5; ++j) e[j] = ep[j];
    float r[6] = {0.f, 0.f, 0.f, 0.f, 0.f, 0.f};
    #pragma unroll
    for (int j = 0; j < 5; ++j) {
        r[0] += e[j] * weff[j * 2];      r[1] += e[j] * weff[j * 2 + 1];
        r[2] += e[j] * weff[10 + j * 2]; r[3] += e[j] * weff[10 + j * 2 + 1];
        r[4] += e[j] * weff[20 + j * 2]; r[5] += e[j] * weff[20 + j * 2 + 1];
    }
    float4* rp = (float4*)(recE + (size_t)k * 8);
    rp[0] = make_float4(r[0], r[1], r[2], r[3]);
    rp[1] = make_float4(r[4], r[5], __int_as_float(s), 0.f);
    int pos = rowptr[d] + atomicAdd(&cur[d], 1);
    iperm[pos] = k;
}

// phase B: gather into dst-sorted order (random 32B READS from L2, coalesced writes)
__global__ void gatherB_kernel(const int* __restrict__ iperm, const float* __restrict__ recE,
                               float* __restrict__ rec) {
    int pos = blockIdx.x * blockDim.x + threadIdx.x;
    if (pos >= N_EDGES) return;
    int k = iperm[pos];
    const float4* sp = (const float4*)(recE + (size_t)k * 8);
    float4 r0 = sp[0];
    float4 r1 = sp[1];
    float4* dp = (float4*)(rec + (size_t)pos * 8);
    dp[0] = r0;
    dp[1] = r1;
}

// ---------------- per-layer kernels ----------------

// 4 threads per node (16-col strips); W in LDS read as float4 (2-way alias = free).
template <int DIN>
__global__ __launch_bounds__(256) void feat_kernel(
    const float* __restrict__ in, const float* __restrict__ W,
    const float* __restrict__ a_s, const float* __restrict__ a_d,
    float* __restrict__ xs, float* __restrict__ a_srcv, float* __restrict__ a_dstv) {
    __shared__ float Wl[DIN * 64];
    __shared__ float asl[64], adl[64];
    int tid = threadIdx.x;
    {
        const float4* Wg = (const float4*)W;
        float4* Wl4 = (float4*)Wl;
        #pragma unroll
        for (int i = tid; i < DIN * 16; i += 256) Wl4[i] = Wg[i];
        if (tid < 64) { asl[tid] = a_s[tid]; adl[tid] = a_d[tid]; }
    }
    __syncthreads();
    int n = blockIdx.x * 64 + (tid >> 2);
    int strip = tid & 3;
    if (n >= N_NODES) return;
    float4 xr[DIN / 4];
    const float4* row4 = (const float4*)(in + (size_t)n * DIN);
    #pragma unroll
    for (int k4 = 0; k4 < DIN / 4; ++k4) xr[k4] = row4[k4];
    float4 acc[4];
    #pragma unroll
    for (int j = 0; j < 4; ++j) acc[j] = make_float4(0.f, 0.f, 0.f, 0.f);
    const float4* W4 = (const float4*)Wl;
    #pragma unroll
    for (int k4 = 0; k4 < DIN / 4; ++k4) {
        float xk[4] = {xr[k4].x, xr[k4].y, xr[k4].z, xr[k4].w};
        #pragma unroll
        for (int kk = 0; kk < 4; ++kk) {
            int k = k4 * 4 + kk;
            #pragma unroll
            for (int j = 0; j < 4; ++j) {
                float4 w = W4[k * 16 + strip * 4 + j];
                acc[j].x += xk[kk] * w.x; acc[j].y += xk[kk] * w.y;
                acc[j].z += xk[kk] * w.z; acc[j].w += xk[kk] * w.w;
            }
        }
    }
    float ps = 0.f, pd = 0.f;
    #pragma unroll
    for (int j = 0; j < 4; ++j) {
        int c = strip * 16 + j * 4;
        ps += acc[j].x * asl[c] + acc[j].y * asl[c + 1] + acc[j].z * asl[c + 2] + acc[j].w * asl[c + 3];
        pd += acc[j].x * adl[c] + acc[j].y * adl[c + 1] + acc[j].z * adl[c + 2] + acc[j].w * adl[c + 3];
    }
    ps += __shfl_xor(ps, 1);
    pd += __shfl_xor(pd, 1);
    if ((strip & 1) == 0) {
        int h = strip >> 1;
        a_srcv[n * 2 + h] = ps;
        a_dstv[n * 2 + h] = pd;
    }
    float4* o = (float4*)(xs + (size_t)n * 64 + strip * 16);
    #pragma unroll
    for (int j = 0; j < 4; ++j) o[j] = acc[j];
}

// 16-lane group per node (16 nodes/block): fused logits + online softmax +
// aggregation + self-loop. Inner loop: 4 edges/iter, 4 gathers in flight.
template <int L>
__global__ __launch_bounds__(256) void node_agg_kernel(
    const int* __restrict__ rowptr, const float* __restrict__ rec,
    const float* __restrict__ a_srcv, const float* __restrict__ a_dstv,
    const float* __restrict__ xs, const float* __restrict__ b,
    float* __restrict__ out, int relu) {
    int nid = (blockIdx.x * 256 + threadIdx.x) >> 4;
    if (nid >= N_NODES) return;
    int lane = threadIdx.x & 63;
    int fl = lane & 15, h = fl >> 3;
    int gbase = lane & 48;                 // group's base lane in wave
    int beg = rowptr[nid], end = rowptr[nid + 1];
    float2 ad2 = ((const float2*)a_dstv)[nid];
    float m0 = -INFINITY, m1 = -INFINITY;
    float4 acc = make_float4(0.f, 0.f, 0.f, 0.f);
    float den0 = 0.f, den1 = 0.f;          // per-lane partials
    float aes0 = 0.f, aes1 = 0.f;          // per-lane partial sums of ae terms
    for (int cb = beg; cb < end; cb += 16) {
        int j = cb + fl;
        float l0 = -INFINITY, l1 = -INFINITY;
        int s = 0;
        if (j < end) {
            const float4* rp = (const float4*)(rec + (size_t)j * 8);
            float4 r0 = rp[0];
            float4 r1 = rp[1];
            s = __float_as_int(r1.z);
            float aex = (L == 0) ? r0.x : (L == 1) ? r0.z : r1.x;
            float aey = (L == 0) ? r0.y : (L == 1) ? r0.w : r1.y;
            aes0 += aex; aes1 += aey;
            float2 as2 = ((const float2*)a_srcv)[s];
            l0 = as2.x + ad2.x + aex;
            l1 = as2.y + ad2.y + aey;
            l0 = (l0 > 0.f) ? l0 : 0.2f * l0;
            l1 = (l1 > 0.f) ? l1 : 0.2f * l1;
        }
        float c0 = l0, c1 = l1;
        #pragma unroll
        for (int o = 8; o; o >>= 1) {      // 16-wide group max
            c0 = fmaxf(c0, __shfl_xor(c0, o));
            c1 = fmaxf(c1, __shfl_xor(c1, o));
        }
        float n0 = fmaxf(m0, c0), n1 = fmaxf(m1, c1);
        float sc0 = expf(m0 - n0), sc1 = expf(m1 - n1);  // first chunk: exp(-inf)=0
        den0 *= sc0; den1 *= sc1;
        float sa = h ? sc1 : sc0;
        acc.x *= sa; acc.y *= sa; acc.z *= sa; acc.w *= sa;
        m0 = n0; m1 = n1;
        float ex0 = expf(l0 - m0);         // invalid lanes -> 0
        float ex1 = expf(l1 - m1);
        den0 += ex0; den1 += ex1;
        int cnt = min(end - cb, 16);
        for (int t4 = 0; t4 < cnt; t4 += 4) {
            int tA = gbase + t4;
            float eA0 = __shfl(ex0, tA),     eA1 = __shfl(ex1, tA);     int sA = __shfl(s, tA);
            float eB0 = __shfl(ex0, tA + 1), eB1 = __shfl(ex1, tA + 1); int sB = __shfl(s, tA + 1);
            float eC0 = __shfl(ex0, tA + 2), eC1 = __shfl(ex1, tA + 2); int sC = __shfl(s, tA + 2);
            float eD0 = __shfl(ex0, tA + 3), eD1 = __shfl(ex1, tA + 3); int sD = __shfl(s, tA + 3);
            float eA = h ? eA1 : eA0, eB = h ? eB1 : eB0;
            float eC = h ? eC1 : eC0, eD = h ? eD1 : eD0;
            float4 xa = *(const float4*)(xs + (size_t)sA * 64 + fl * 4);
            float4 xb = *(const float4*)(xs + (size_t)sB * 64 + fl * 4);
            float4 xc = *(const float4*)(xs + (size_t)sC * 64 + fl * 4);
            float4 xd = *(const float4*)(xs + (size_t)sD * 64 + fl * 4);
            acc.x += eA * xa.x + eB * xb.x + eC * xc.x + eD * xd.x;
            acc.y += eA * xa.y + eB * xb.y + eC * xc.y + eD * xd.y;
            acc.z += eA * xa.z + eB * xb.z + eC * xc.z + eD * xd.z;
            acc.w += eA * xa.w + eB * xb.w + eC * xc.w + eD * xd.w;
        }
    }
    #pragma unroll
    for (int o = 8; o; o >>= 1) {          // 16-wide reduces
        den0 += __shfl_xor(den0, o); den1 += __shfl_xor(den1, o);
        aes0 += __shfl_xor(aes0, o); aes1 += __shfl_xor(aes1, o);
    }
    int ne = end - beg;
    float aeS = (h ? aes1 : aes0) / fmaxf((float)ne, 1.f);
    float2 as2 = ((const float2*)a_srcv)[nid];
    float ls = (h ? as2.y + ad2.y : as2.x + ad2.x) + aeS;
    ls = (ls > 0.f) ? ls : 0.2f * ls;
    float mh = h ? m1 : m0;
    float nm = fmaxf(mh, ls);
    float sc = expf(mh - nm);              // ne==0: exp(-inf)=0
    float exS = expf(ls - nm);
    float den = (h ? den1 : den0) * sc + exS;
    float4 xv = *(const float4*)(xs + (size_t)nid * 64 + fl * 4);
    float inv = 1.f / (den + 1e-16f);
    float4 b4 = ((const float4*)b)[fl];
    float4 v;
    v.x = (acc.x * sc + exS * xv.x) * inv + b4.x;
    v.y = (acc.y * sc + exS * xv.y) * inv + b4.y;
    v.z = (acc.z * sc + exS * xv.z) * inv + b4.z;
    v.w = (acc.w * sc + exS * xv.w) * inv + b4.w;
    if (relu) {
        v.x = fmaxf(v.x, 0.f); v.y = fmaxf(v.y, 0.f);
        v.z = fmaxf(v.z, 0.f); v.w = fmaxf(v.w, 0.f);
    }
    ((float4*)(out + (size_t)nid * 64))[fl] = v;
}

// ---------------- tail: pool + head fused (block g handles group g) ----------------

__global__ __launch_bounds__(256) void pool_head_kernel(
    const float* __restrict__ hfeat, const int* __restrict__ gstart,
    const float* __restrict__ Wl, const float* __restrict__ bl,
    float* __restrict__ out) {
    __shared__ float sm[4][64];
    __shared__ float pooledL[64];
    int g = blockIdx.x;
    int w = threadIdx.x >> 6, lane = threadIdx.x & 63;
    int beg = gstart[g], end = gstart[g + 1];
    float acc = 0.f;
    for (int n = beg + w; n < end; n += 4)
        acc += hfeat[(size_t)n * 64 + lane];
    sm[w][lane] = acc;
    __syncthreads();
    if (w == 0) {
        float v = sm[0][lane] + sm[1][lane] + sm[2][lane] + sm[3][lane];
        pooledL[lane] = v / fmaxf((float)(end - beg), 1.f);
    }
    __syncthreads();
    if (threadIdx.x < N_ACT) {
        int a = threadIdx.x;
        float s = bl[a];
        #pragma unroll
        for (int j = 0; j < 64; ++j) s += pooledL[j] * Wl[j * 8 + a];
        out[g * N_ACT + a] = tanhf(s);
    }
}

extern "C" void kernel_launch(void* const* d_in, const int* in_sizes, int n_in,
                              void* d_out, int out_size, void* d_ws, size_t ws_size,
                              hipStream_t stream) {
    const float* x    = (const float*)d_in[0];
    const int*   ei   = (const int*)d_in[1];
    const float* ea   = (const float*)d_in[2];
    const int*   batch= (const int*)d_in[3];
    const float* W[3]   = {(const float*)d_in[4],  (const float*)d_in[10], (const float*)d_in[16]};
    const float* We[3]  = {(const float*)d_in[5],  (const float*)d_in[11], (const float*)d_in[17]};
    const float* as_[3] = {(const float*)d_in[6],  (const float*)d_in[12], (const float*)d_in[18]};
    const float* ad_[3] = {(const float*)d_in[7],  (const float*)d_in[13], (const float*)d_in[19]};
    const float* ae_[3] = {(const float*)d_in[8],  (const float*)d_in[14], (const float*)d_in[20]};
    const float* b_[3]  = {(const float*)d_in[9],  (const float*)d_in[15], (const float*)d_in[21]};
    const float* Wlin = (const float*)d_in[22];
    const float* bl   = (const float*)d_in[23];
    float* out = (float*)d_out;

    float* ws = (float*)d_ws;
    size_t off = 0;
    float* A      = ws + off; off += (size_t)N_NODES * 64;   // layer io
    float* B      = ws + off; off += (size_t)N_NODES * 64;   // xs
    // recE aliases A+B: 800000*8 floats == 2 * 50000*64 floats exactly.
    // It is fully consumed by gatherB_kernel before feat/node_agg write A/B.
    float* recE   = A;
    float* rec    = ws + off; off += (size_t)N_EDGES * 8;    // dst-sorted records
    float* a_srcv = ws + off; off += N_NODES * 2;
    float* a_dstv = ws + off; off += N_NODES * 2;
    float* weff   = ws + off; off += 32;
    int* rowptr = (int*)(ws + off); off += N_NODES + 1;
    int* hist   = (int*)(ws + off); off += N_NODES;          // hist+cur contiguous
    int* cur    = (int*)(ws + off); off += N_NODES;
    int* gstart = (int*)(ws + off); off += N_G + 1;
    int* bsum   = (int*)(ws + off); off += SNB;
    int* iperm  = (int*)(ws + off); off += N_EDGES;

    // ---- once-per-call setup ----
    hipMemsetAsync(hist, 0, 2 * N_NODES * sizeof(int), stream);   // hist + cur
    setup_kernel<<<1 + (N_EDGES + 255) / 256, 256, 0, stream>>>(
        ei, batch, We[0], ae_[0], We[1], ae_[1], We[2], ae_[2], weff, gstart, hist);
    scan_bsum_kernel<<<SNB, SBLK, 0, stream>>>(hist, bsum);
    scan_rowptr_kernel<<<SNB, SBLK, 0, stream>>>(hist, bsum, rowptr);
    scatterA_kernel<<<(N_EDGES + 255) / 256, 256, 0, stream>>>(ei, ea, weff, rowptr, cur,
                                                               recE, iperm);
    gatherB_kernel<<<(N_EDGES + 255) / 256, 256, 0, stream>>>(iperm, recE, rec);

    const int NB = (N_NODES * 16 + 255) / 256;   // 16 nodes per block
    const int FB = (N_NODES + 63) / 64;
    for (int l = 0; l < 3; ++l) {
        if (l == 0)
            feat_kernel<32><<<FB, 256, 0, stream>>>(x, W[0], as_[0], ad_[0], B, a_srcv, a_dstv);
        else
            feat_kernel<64><<<FB, 256, 0, stream>>>(A, W[l], as_[l], ad_[l], B, a_srcv, a_dstv);
        if (l == 0)
            node_agg_kernel<0><<<NB, 256, 0, stream>>>(rowptr, rec, a_srcv, a_dstv, B, b_[0], A, 1);
        else if (l == 1)
            node_agg_kernel<1><<<NB, 256, 0, stream>>>(rowptr, rec, a_srcv, a_dstv, B, b_[1], A, 1);
        else
            node_agg_kernel<2><<<NB, 256, 0, stream>>>(rowptr, rec, a_srcv, a_dstv, B, b_[2], A, 0);
    }
    pool_head_kernel<<<N_G, 256, 0, stream>>>(A, gstart, Wlin, bl, out);
}

// Round 13
// 391.472 us; speedup vs baseline: 1.0353x; 1.0353x over previous
//
#include <hip/hip_runtime.h>
#include <math.h>

#define N_NODES 50000
#define N_EDGES 800000
#define E_DIM   5
#define N_G     128
#define N_ACT   8
#define SBLK    512
#define SNB     ((N_NODES + SBLK - 1) / SBLK)   // 98

// ---------------- once-per-call setup ----------------

// block 0: weff (t in [160,190)) + gstart (t in [0,129)); blocks 1..: hist
__global__ __launch_bounds__(256) void setup_kernel(
    const int* __restrict__ ei, const int* __restrict__ batch,
    const float* __restrict__ We1, const float* __restrict__ ae1,
    const float* __restrict__ We2, const float* __restrict__ ae2,
    const float* __restrict__ We3, const float* __restrict__ ae3,
    float* __restrict__ weff, int* __restrict__ gstart, int* __restrict__ hist) {
    int bid = blockIdx.x, tid = threadIdx.x;
    if (bid == 0) {
        if (tid <= N_G) {  // group boundaries in sorted batch
            int g = tid, lo = 0, hi = N_NODES;
            while (lo < hi) { int mid = (lo + hi) >> 1; if (batch[mid] < g) lo = mid + 1; else hi = mid; }
            gstart[g] = lo;
        }
        int t = tid - 160;
        if (t >= 0 && t < 30) {  // weff[l*10 + d*2 + h] = sum_c We_l[d, h*32+c]*ae_l[h,c]
            int l = t / 10, r = t % 10, d = r >> 1, h = r & 1;
            const float* We = (l == 0) ? We1 : (l == 1) ? We2 : We3;
            const float* ae = (l == 0) ? ae1 : (l == 1) ? ae2 : ae3;
            float s = 0.f;
            for (int c = 0; c < 32; ++c) s += We[d * 64 + h * 32 + c] * ae[h * 32 + c];
            weff[l * 10 + d * 2 + h] = s;
        }
        return;
    }
    int k = (bid - 1) * 256 + tid;
    if (k < N_EDGES) atomicAdd(&hist[ei[N_EDGES + k]], 1);
}

__device__ __forceinline__ int wave_incl_scan(int v, int lane) {
    #pragma unroll
    for (int off = 1; off < 64; off <<= 1) {
        int n = __shfl_up(v, off);
        if (lane >= off) v += n;
    }
    return v;
}

__global__ __launch_bounds__(SBLK) void scan_bsum_kernel(const int* __restrict__ hist,
                                                         int* __restrict__ bsum) {
    int i = blockIdx.x * SBLK + threadIdx.x;
    int v = (i < N_NODES) ? hist[i] : 0;
    __shared__ int sm[SBLK / 64];
    int lane = threadIdx.x & 63, w = threadIdx.x >> 6;
    #pragma unroll
    for (int o = 32; o; o >>= 1) v += __shfl_xor(v, o);
    if (lane == 0) sm[w] = v;
    __syncthreads();
    if (threadIdx.x == 0) {
        int s = 0;
        #pragma unroll
        for (int k = 0; k < SBLK / 64; ++k) s += sm[k];
        bsum[blockIdx.x] = s;
    }
}

// rowptr scan; each block derives its own offset from bsum (<= 97 partials)
__global__ __launch_bounds__(SBLK) void scan_rowptr_kernel(const int* __restrict__ hist,
                                                           const int* __restrict__ bsum,
                                                           int* __restrict__ rowptr) {
    __shared__ int s_boffs;
    __shared__ int wtot[SBLK / 64];
    int bid = blockIdx.x;
    if (threadIdx.x < 64) {
        int v = 0;
        for (int i = threadIdx.x; i < bid; i += 64) v += bsum[i];
        #pragma unroll
        for (int o = 32; o; o >>= 1) v += __shfl_xor(v, o);
        if (threadIdx.x == 0) s_boffs = v;
    }
    int i = bid * SBLK + threadIdx.x;
    int v = (i < N_NODES) ? hist[i] : 0;
    int lane = threadIdx.x & 63, w = threadIdx.x >> 6;
    int inc = wave_incl_scan(v, lane);
    if (lane == 63) wtot[w] = inc;
    __syncthreads();
    int woff = 0;
    for (int k = 0; k < w; ++k) woff += wtot[k];
    int excl = s_boffs + woff + inc - v;
    if (i < N_NODES) rowptr[i] = excl;
    if (i == N_NODES - 1) rowptr[N_NODES] = excl + v;
}

// scatter real edges dst-sorted into packed 32B records (single phase, R6-proven):
// rec[pos*8 + {0..5}] = e . weff_{l0,l1,l2}, [6]=src bits, [7]=pad
__global__ void scatter_kernel(const int* __restrict__ ei, const float* __restrict__ ea,
                               const float* __restrict__ weff,
                               const int* __restrict__ rowptr, int* __restrict__ cur,
                               float* __restrict__ rec) {
    int k = blockIdx.x * blockDim.x + threadIdx.x;
    if (k >= N_EDGES) return;
    int s = ei[k], d = ei[N_EDGES + k];
    const float* ep = ea + (size_t)k * E_DIM;
    float e[5];
    #pragma unroll
    for (int j = 0; j < 5; ++j) e[j] = ep[j];
    float r[6] = {0.f, 0.f, 0.f, 0.f, 0.f, 0.f};
    #pragma unroll
    for (int j = 0; j < 5; ++j) {
        r[0] += e[j] * weff[j * 2];      r[1] += e[j] * weff[j * 2 + 1];
        r[2] += e[j] * weff[10 + j * 2]; r[3] += e[j] * weff[10 + j * 2 + 1];
        r[4] += e[j] * weff[20 + j * 2]; r[5] += e[j] * weff[20 + j * 2 + 1];
    }
    int pos = rowptr[d] + atomicAdd(&cur[d], 1);
    float4* rp = (float4*)(rec + (size_t)pos * 8);
    rp[0] = make_float4(r[0], r[1], r[2], r[3]);
    rp[1] = make_float4(r[4], r[5], __int_as_float(s), 0.f);
}

// ---------------- per-layer kernels ----------------

// 4 threads per node (16-col strips); W in LDS read as float4 (2-way alias = free).
template <int DIN>
__global__ __launch_bounds__(256) void feat_kernel(
    const float* __restrict__ in, const float* __restrict__ W,
    const float* __restrict__ a_s, const float* __restrict__ a_d,
    float* __restrict__ xs, float* __restrict__ a_srcv, float* __restrict__ a_dstv) {
    __shared__ float Wl[DIN * 64];
    __shared__ float asl[64], adl[64];
    int tid = threadIdx.x;
    {
        const float4* Wg = (const float4*)W;
        float4* Wl4 = (float4*)Wl;
        #pragma unroll
        for (int i = tid; i < DIN * 16; i += 256) Wl4[i] = Wg[i];
        if (tid < 64) { asl[tid] = a_s[tid]; adl[tid] = a_d[tid]; }
    }
    __syncthreads();
    int n = blockIdx.x * 64 + (tid >> 2);
    int strip = tid & 3;
    if (n >= N_NODES) return;
    float4 xr[DIN / 4];
    const float4* row4 = (const float4*)(in + (size_t)n * DIN);
    #pragma unroll
    for (int k4 = 0; k4 < DIN / 4; ++k4) xr[k4] = row4[k4];
    float4 acc[4];
    #pragma unroll
    for (int j = 0; j < 4; ++j) acc[j] = make_float4(0.f, 0.f, 0.f, 0.f);
    const float4* W4 = (const float4*)Wl;
    #pragma unroll
    for (int k4 = 0; k4 < DIN / 4; ++k4) {
        float xk[4] = {xr[k4].x, xr[k4].y, xr[k4].z, xr[k4].w};
        #pragma unroll
        for (int kk = 0; kk < 4; ++kk) {
            int k = k4 * 4 + kk;
            #pragma unroll
            for (int j = 0; j < 4; ++j) {
                float4 w = W4[k * 16 + strip * 4 + j];
                acc[j].x += xk[kk] * w.x; acc[j].y += xk[kk] * w.y;
                acc[j].z += xk[kk] * w.z; acc[j].w += xk[kk] * w.w;
            }
        }
    }
    float ps = 0.f, pd = 0.f;
    #pragma unroll
    for (int j = 0; j < 4; ++j) {
        int c = strip * 16 + j * 4;
        ps += acc[j].x * asl[c] + acc[j].y * asl[c + 1] + acc[j].z * asl[c + 2] + acc[j].w * asl[c + 3];
        pd += acc[j].x * adl[c] + acc[j].y * adl[c + 1] + acc[j].z * adl[c + 2] + acc[j].w * adl[c + 3];
    }
    ps += __shfl_xor(ps, 1);
    pd += __shfl_xor(pd, 1);
    if ((strip & 1) == 0) {
        int h = strip >> 1;
        a_srcv[n * 2 + h] = ps;
        a_dstv[n * 2 + h] = pd;
    }
    float4* o = (float4*)(xs + (size_t)n * 64 + strip * 16);
    #pragma unroll
    for (int j = 0; j < 4; ++j) o[j] = acc[j];
}

// 16-lane group per node, TWO-PASS softmax:
// pass 1: per-lane online (m,den) per head (no shfl in loop) + aes sums; 16-wide merge;
//         self-loop folded analytically -> final M, den.
// pass 2: dependency-free ex=exp(l-M) + quad-broadcast gather-sum (4 gathers in flight).
template <int L>
__global__ __launch_bounds__(256) void node_agg_kernel(
    const int* __restrict__ rowptr, const float* __restrict__ rec,
    const float* __restrict__ a_srcv, const float* __restrict__ a_dstv,
    const float* __restrict__ xs, const float* __restrict__ b,
    float* __restrict__ out, int relu) {
    int nid = (blockIdx.x * 256 + threadIdx.x) >> 4;
    if (nid >= N_NODES) return;
    int lane = threadIdx.x & 63;
    int fl = lane & 15, h = fl >> 3;
    int gbase = lane & 48;                 // group's base lane in wave
    int beg = rowptr[nid], end = rowptr[nid + 1];
    float2 ad2 = ((const float2*)a_dstv)[nid];

    // ---- pass 1 ----
    float m0 = -INFINITY, m1 = -INFINITY, d0 = 0.f, d1 = 0.f;
    float aes0 = 0.f, aes1 = 0.f;
    for (int j = beg + fl; j < end; j += 16) {
        const float4* rp = (const float4*)(rec + (size_t)j * 8);
        float4 r0 = rp[0];
        float4 r1 = rp[1];
        int s = __float_as_int(r1.z);
        float aex = (L == 0) ? r0.x : (L == 1) ? r0.z : r1.x;
        float aey = (L == 0) ? r0.y : (L == 1) ? r0.w : r1.y;
        aes0 += aex; aes1 += aey;
        float2 as2 = ((const float2*)a_srcv)[s];
        float l0 = as2.x + ad2.x + aex;
        float l1 = as2.y + ad2.y + aey;
        l0 = (l0 > 0.f) ? l0 : 0.2f * l0;
        l1 = (l1 > 0.f) ? l1 : 0.2f * l1;
        float n0 = fmaxf(m0, l0);          // m0=-inf first iter: exp(-inf)=0
        d0 = d0 * __expf(m0 - n0) + __expf(l0 - n0); m0 = n0;
        float n1 = fmaxf(m1, l1);
        d1 = d1 * __expf(m1 - n1) + __expf(l1 - n1); m1 = n1;
    }
    #pragma unroll
    for (int o = 8; o; o >>= 1) {          // 16-wide merge (all lanes converge)
        float mo0 = __shfl_xor(m0, o), do0 = __shfl_xor(d0, o);
        float mo1 = __shfl_xor(m1, o), do1 = __shfl_xor(d1, o);
        float n0 = fmaxf(m0, mo0);
        float ea0 = (m0 == n0) ? 1.f : __expf(m0 - n0);
        float eb0 = (mo0 == n0) ? 1.f : __expf(mo0 - n0);
        d0 = d0 * ea0 + do0 * eb0; m0 = n0;
        float n1 = fmaxf(m1, mo1);
        float ea1 = (m1 == n1) ? 1.f : __expf(m1 - n1);
        float eb1 = (mo1 == n1) ? 1.f : __expf(mo1 - n1);
        d1 = d1 * ea1 + do1 * eb1; m1 = n1;
        aes0 += __shfl_xor(aes0, o);
        aes1 += __shfl_xor(aes1, o);
    }
    // ---- self-loop fold ----
    int ne = end - beg;
    float invne = 1.f / fmaxf((float)ne, 1.f);
    float2 as2n = ((const float2*)a_srcv)[nid];
    float ls0 = as2n.x + ad2.x + aes0 * invne;
    float ls1 = as2n.y + ad2.y + aes1 * invne;
    ls0 = (ls0 > 0.f) ? ls0 : 0.2f * ls0;
    ls1 = (ls1 > 0.f) ? ls1 : 0.2f * ls1;
    float M0 = fmaxf(m0, ls0), M1 = fmaxf(m1, ls1);
    float sc0 = (m0 == M0) ? 1.f : __expf(m0 - M0);   // deg0: m0=-inf -> exp(-inf)=0
    float sc1 = (m1 == M1) ? 1.f : __expf(m1 - M1);
    float exS0 = __expf(ls0 - M0), exS1 = __expf(ls1 - M1);
    float den0 = d0 * sc0 + exS0;
    float den1 = d1 * sc1 + exS1;

    // ---- pass 2 ----
    float4 acc = make_float4(0.f, 0.f, 0.f, 0.f);
    for (int cb = beg; cb < end; cb += 16) {
        int j = cb + fl;
        float ex0 = 0.f, ex1 = 0.f;
        int s = 0;
        if (j < end) {
            const float4* rp = (const float4*)(rec + (size_t)j * 8);
            float4 r0 = rp[0];
            float4 r1 = rp[1];
            s = __float_as_int(r1.z);
            float aex = (L == 0) ? r0.x : (L == 1) ? r0.z : r1.x;
            float aey = (L == 0) ? r0.y : (L == 1) ? r0.w : r1.y;
            float2 as2 = ((const float2*)a_srcv)[s];
            float l0 = as2.x + ad2.x + aex;
            float l1 = as2.y + ad2.y + aey;
            l0 = (l0 > 0.f) ? l0 : 0.2f * l0;
            l1 = (l1 > 0.f) ? l1 : 0.2f * l1;
            ex0 = __expf(l0 - M0);
            ex1 = __expf(l1 - M1);
        }
        int cnt = min(end - cb, 16);
        for (int t4 = 0; t4 < cnt; t4 += 4) {
            int tA = gbase + t4;
            float eA0 = __shfl(ex0, tA),     eA1 = __shfl(ex1, tA);     int sA = __shfl(s, tA);
            float eB0 = __shfl(ex0, tA + 1), eB1 = __shfl(ex1, tA + 1); int sB = __shfl(s, tA + 1);
            float eC0 = __shfl(ex0, tA + 2), eC1 = __shfl(ex1, tA + 2); int sC = __shfl(s, tA + 2);
            float eD0 = __shfl(ex0, tA + 3), eD1 = __shfl(ex1, tA + 3); int sD = __shfl(s, tA + 3);
            float eA = h ? eA1 : eA0, eB = h ? eB1 : eB0;
            float eC = h ? eC1 : eC0, eD = h ? eD1 : eD0;
            float4 xa = *(const float4*)(xs + (size_t)sA * 64 + fl * 4);
            float4 xb = *(const float4*)(xs + (size_t)sB * 64 + fl * 4);
            float4 xc = *(const float4*)(xs + (size_t)sC * 64 + fl * 4);
            float4 xd = *(const float4*)(xs + (size_t)sD * 64 + fl * 4);
            acc.x += eA * xa.x + eB * xb.x + eC * xc.x + eD * xd.x;
            acc.y += eA * xa.y + eB * xb.y + eC * xc.y + eD * xd.y;
            acc.z += eA * xa.z + eB * xb.z + eC * xc.z + eD * xd.z;
            acc.w += eA * xa.w + eB * xb.w + eC * xc.w + eD * xd.w;
        }
    }
    // self-loop contribution + epilogue
    float exSh = h ? exS1 : exS0;
    float den  = (h ? den1 : den0) + 1e-16f;
    float4 xv = *(const float4*)(xs + (size_t)nid * 64 + fl * 4);
    float inv = 1.f / den;
    float4 b4 = ((const float4*)b)[fl];
    float4 v;
    v.x = (acc.x + exSh * xv.x) * inv + b4.x;
    v.y = (acc.y + exSh * xv.y) * inv + b4.y;
    v.z = (acc.z + exSh * xv.z) * inv + b4.z;
    v.w = (acc.w + exSh * xv.w) * inv + b4.w;
    if (relu) {
        v.x = fmaxf(v.x, 0.f); v.y = fmaxf(v.y, 0.f);
        v.z = fmaxf(v.z, 0.f); v.w = fmaxf(v.w, 0.f);
    }
    ((float4*)(out + (size_t)nid * 64))[fl] = v;
}

// ---------------- tail: pool + head fused (block g handles group g) ----------------

__global__ __launch_bounds__(256) void pool_head_kernel(
    const float* __restrict__ hfeat, const int* __restrict__ gstart,
    const float* __restrict__ Wl, const float* __restrict__ bl,
    float* __restrict__ out) {
    __shared__ float sm[4][64];
    __shared__ float pooledL[64];
    int g = blockIdx.x;
    int w = threadIdx.x >> 6, lane = threadIdx.x & 63;
    int beg = gstart[g], end = gstart[g + 1];
    float acc = 0.f;
    for (int n = beg + w; n < end; n += 4)
        acc += hfeat[(size_t)n * 64 + lane];
    sm[w][lane] = acc;
    __syncthreads();
    if (w == 0) {
        float v = sm[0][lane] + sm[1][lane] + sm[2][lane] + sm[3][lane];
        pooledL[lane] = v / fmaxf((float)(end - beg), 1.f);
    }
    __syncthreads();
    if (threadIdx.x < N_ACT) {
        int a = threadIdx.x;
        float s = bl[a];
        #pragma unroll
        for (int j = 0; j < 64; ++j) s += pooledL[j] * Wl[j * 8 + a];
        out[g * N_ACT + a] = tanhf(s);
    }
}

extern "C" void kernel_launch(void* const* d_in, const int* in_sizes, int n_in,
                              void* d_out, int out_size, void* d_ws, size_t ws_size,
                              hipStream_t stream) {
    const float* x    = (const float*)d_in[0];
    const int*   ei   = (const int*)d_in[1];
    const float* ea   = (const float*)d_in[2];
    const int*   batch= (const int*)d_in[3];
    const float* W[3]   = {(const float*)d_in[4],  (const float*)d_in[10], (const float*)d_in[16]};
    const float* We[3]  = {(const float*)d_in[5],  (const float*)d_in[11], (const float*)d_in[17]};
    const float* as_[3] = {(const float*)d_in[6],  (const float*)d_in[12], (const float*)d_in[18]};
    const float* ad_[3] = {(const float*)d_in[7],  (const float*)d_in[13], (const float*)d_in[19]};
    const float* ae_[3] = {(const float*)d_in[8],  (const float*)d_in[14], (const float*)d_in[20]};
    const float* b_[3]  = {(const float*)d_in[9],  (const float*)d_in[15], (const float*)d_in[21]};
    const float* Wlin = (const float*)d_in[22];
    const float* bl   = (const float*)d_in[23];
    float* out = (float*)d_out;

    float* ws = (float*)d_ws;
    size_t off = 0;
    float* A      = ws + off; off += (size_t)N_NODES * 64;   // layer io
    float* B      = ws + off; off += (size_t)N_NODES * 64;   // xs
    float* rec    = ws + off; off += (size_t)N_EDGES * 8;    // dst-sorted records
    float* a_srcv = ws + off; off += N_NODES * 2;
    float* a_dstv = ws + off; off += N_NODES * 2;
    float* weff   = ws + off; off += 32;
    int* rowptr = (int*)(ws + off); off += N_NODES + 1;
    int* hist   = (int*)(ws + off); off += N_NODES;          // hist+cur contiguous
    int* cur    = (int*)(ws + off); off += N_NODES;
    int* gstart = (int*)(ws + off); off += N_G + 1;
    int* bsum   = (int*)(ws + off); off += SNB;

    // ---- once-per-call setup ----
    hipMemsetAsync(hist, 0, 2 * N_NODES * sizeof(int), stream);   // hist + cur
    setup_kernel<<<1 + (N_EDGES + 255) / 256, 256, 0, stream>>>(
        ei, batch, We[0], ae_[0], We[1], ae_[1], We[2], ae_[2], weff, gstart, hist);
    scan_bsum_kernel<<<SNB, SBLK, 0, stream>>>(hist, bsum);
    scan_rowptr_kernel<<<SNB, SBLK, 0, stream>>>(hist, bsum, rowptr);
    scatter_kernel<<<(N_EDGES + 255) / 256, 256, 0, stream>>>(ei, ea, weff, rowptr, cur, rec);

    const int NB = (N_NODES * 16 + 255) / 256;   // 16 nodes per block
    const int FB = (N_NODES + 63) / 64;
    for (int l = 0; l < 3; ++l) {
        if (l == 0)
            feat_kernel<32><<<FB, 256, 0, stream>>>(x, W[0], as_[0], ad_[0], B, a_srcv, a_dstv);
        else
            feat_kernel<64><<<FB, 256, 0, stream>>>(A, W[l], as_[l], ad_[l], B, a_srcv, a_dstv);
        if (l == 0)
            node_agg_kernel<0><<<NB, 256, 0, stream>>>(rowptr, rec, a_srcv, a_dstv, B, b_[0], A, 1);
        else if (l == 1)
            node_agg_kernel<1><<<NB, 256, 0, stream>>>(rowptr, rec, a_srcv, a_dstv, B, b_[1], A, 1);
        else
            node_agg_kernel<2><<<NB, 256, 0, stream>>>(rowptr, rec, a_srcv, a_dstv, B, b_[2], A, 0);
    }
    pool_head_kernel<<<N_G, 256, 0, stream>>>(A, gstart, Wlin, bl, out);
}

// Round 14
// 344.800 us; speedup vs baseline: 1.1755x; 1.1354x over previous
//
#include <hip/hip_runtime.h>
#include <hip/hip_fp16.h>
#include <math.h>

#define N_NODES 50000
#define N_EDGES 800000
#define N_EH    400000   // N_EDGES / 2
#define E_DIM   5
#define N_G     128
#define N_ACT   8
#define SBLK    512
#define SNB     ((N_NODES + SBLK - 1) / SBLK)   // 98

// ---------------- once-per-call setup ----------------

// block 0: weff (t in [160,190)) + gstart (t in [0,129)); blocks 1..: hist
__global__ __launch_bounds__(256) void setup_kernel(
    const int* __restrict__ ei, const int* __restrict__ batch,
    const float* __restrict__ We1, const float* __restrict__ ae1,
    const float* __restrict__ We2, const float* __restrict__ ae2,
    const float* __restrict__ We3, const float* __restrict__ ae3,
    float* __restrict__ weff, int* __restrict__ gstart, int* __restrict__ hist) {
    int bid = blockIdx.x, tid = threadIdx.x;
    if (bid == 0) {
        if (tid <= N_G) {  // group boundaries in sorted batch
            int g = tid, lo = 0, hi = N_NODES;
            while (lo < hi) { int mid = (lo + hi) >> 1; if (batch[mid] < g) lo = mid + 1; else hi = mid; }
            gstart[g] = lo;
        }
        int t = tid - 160;
        if (t >= 0 && t < 30) {  // weff[l*10 + d*2 + h] = sum_c We_l[d, h*32+c]*ae_l[h,c]
            int l = t / 10, r = t % 10, d = r >> 1, h = r & 1;
            const float* We = (l == 0) ? We1 : (l == 1) ? We2 : We3;
            const float* ae = (l == 0) ? ae1 : (l == 1) ? ae2 : ae3;
            float s = 0.f;
            for (int c = 0; c < 32; ++c) s += We[d * 64 + h * 32 + c] * ae[h * 32 + c];
            weff[l * 10 + d * 2 + h] = s;
        }
        return;
    }
    int k = (bid - 1) * 256 + tid;
    if (k < N_EDGES) atomicAdd(&hist[ei[N_EDGES + k]], 1);
}

__device__ __forceinline__ int wave_incl_scan(int v, int lane) {
    #pragma unroll
    for (int off = 1; off < 64; off <<= 1) {
        int n = __shfl_up(v, off);
        if (lane >= off) v += n;
    }
    return v;
}

__global__ __launch_bounds__(SBLK) void scan_bsum_kernel(const int* __restrict__ hist,
                                                         int* __restrict__ bsum) {
    int i = blockIdx.x * SBLK + threadIdx.x;
    int v = (i < N_NODES) ? hist[i] : 0;
    __shared__ int sm[SBLK / 64];
    int lane = threadIdx.x & 63, w = threadIdx.x >> 6;
    #pragma unroll
    for (int o = 32; o; o >>= 1) v += __shfl_xor(v, o);
    if (lane == 0) sm[w] = v;
    __syncthreads();
    if (threadIdx.x == 0) {
        int s = 0;
        #pragma unroll
        for (int k = 0; k < SBLK / 64; ++k) s += sm[k];
        bsum[blockIdx.x] = s;
    }
}

// rowptr scan; each block derives its own offset from bsum (<= 97 partials)
__global__ __launch_bounds__(SBLK) void scan_rowptr_kernel(const int* __restrict__ hist,
                                                           const int* __restrict__ bsum,
                                                           int* __restrict__ rowptr) {
    __shared__ int s_boffs;
    __shared__ int wtot[SBLK / 64];
    int bid = blockIdx.x;
    if (threadIdx.x < 64) {
        int v = 0;
        for (int i = threadIdx.x; i < bid; i += 64) v += bsum[i];
        #pragma unroll
        for (int o = 32; o; o >>= 1) v += __shfl_xor(v, o);
        if (threadIdx.x == 0) s_boffs = v;
    }
    int i = bid * SBLK + threadIdx.x;
    int v = (i < N_NODES) ? hist[i] : 0;
    int lane = threadIdx.x & 63, w = threadIdx.x >> 6;
    int inc = wave_incl_scan(v, lane);
    if (lane == 63) wtot[w] = inc;
    __syncthreads();
    int woff = 0;
    for (int k = 0; k < w; ++k) woff += wtot[k];
    int excl = s_boffs + woff + inc - v;
    if (i < N_NODES) rowptr[i] = excl;
    if (i == N_NODES - 1) rowptr[N_NODES] = excl + v;
}

// scatter into 16B records: {half2 ae_l0, half2 ae_l1, half2 ae_l2, int src}.
// Two independent edges per thread (latency-bound kernel: 2 chains in flight).
__global__ void scatter_kernel(const int* __restrict__ ei, const float* __restrict__ ea,
                               const float* __restrict__ weff,
                               const int* __restrict__ rowptr, int* __restrict__ cur,
                               int4* __restrict__ rec) {
    int k1 = blockIdx.x * blockDim.x + threadIdx.x;
    if (k1 >= N_EH) return;
    int k2 = k1 + N_EH;
    int s1 = ei[k1], d1 = ei[N_EDGES + k1];
    int s2 = ei[k2], d2 = ei[N_EDGES + k2];
    const float* e1 = ea + (size_t)k1 * E_DIM;
    const float* e2 = ea + (size_t)k2 * E_DIM;
    float r1[6] = {0, 0, 0, 0, 0, 0}, r2[6] = {0, 0, 0, 0, 0, 0};
    #pragma unroll
    for (int j = 0; j < 5; ++j) {
        float a = e1[j], b = e2[j];
        #pragma unroll
        for (int q = 0; q < 3; ++q) {
            r1[2 * q]     += a * weff[10 * q + j * 2];
            r1[2 * q + 1] += a * weff[10 * q + j * 2 + 1];
            r2[2 * q]     += b * weff[10 * q + j * 2];
            r2[2 * q + 1] += b * weff[10 * q + j * 2 + 1];
        }
    }
    union { __half2 h; int i; } u;
    int4 v1, v2;
    u.h = __floats2half2_rn(r1[0], r1[1]); v1.x = u.i;
    u.h = __floats2half2_rn(r1[2], r1[3]); v1.y = u.i;
    u.h = __floats2half2_rn(r1[4], r1[5]); v1.z = u.i;
    v1.w = s1;
    u.h = __floats2half2_rn(r2[0], r2[1]); v2.x = u.i;
    u.h = __floats2half2_rn(r2[2], r2[3]); v2.y = u.i;
    u.h = __floats2half2_rn(r2[4], r2[5]); v2.z = u.i;
    v2.w = s2;
    int p1 = rowptr[d1] + atomicAdd(&cur[d1], 1);
    int p2 = rowptr[d2] + atomicAdd(&cur[d2], 1);
    rec[p1] = v1;
    rec[p2] = v2;
}

// ---------------- per-layer kernels ----------------

// 4 threads per node (16-col strips); W in LDS read as float4 (2-way alias = free).
// xs output is fp16 (halves the gather traffic in node_agg).
template <int DIN>
__global__ __launch_bounds__(256) void feat_kernel(
    const float* __restrict__ in, const float* __restrict__ W,
    const float* __restrict__ a_s, const float* __restrict__ a_d,
    __half* __restrict__ xs, float* __restrict__ a_srcv, float* __restrict__ a_dstv) {
    __shared__ float Wl[DIN * 64];
    __shared__ float asl[64], adl[64];
    int tid = threadIdx.x;
    {
        const float4* Wg = (const float4*)W;
        float4* Wl4 = (float4*)Wl;
        #pragma unroll
        for (int i = tid; i < DIN * 16; i += 256) Wl4[i] = Wg[i];
        if (tid < 64) { asl[tid] = a_s[tid]; adl[tid] = a_d[tid]; }
    }
    __syncthreads();
    int n = blockIdx.x * 64 + (tid >> 2);
    int strip = tid & 3;
    if (n >= N_NODES) return;
    float4 xr[DIN / 4];
    const float4* row4 = (const float4*)(in + (size_t)n * DIN);
    #pragma unroll
    for (int k4 = 0; k4 < DIN / 4; ++k4) xr[k4] = row4[k4];
    float4 acc[4];
    #pragma unroll
    for (int j = 0; j < 4; ++j) acc[j] = make_float4(0.f, 0.f, 0.f, 0.f);
    const float4* W4 = (const float4*)Wl;
    #pragma unroll
    for (int k4 = 0; k4 < DIN / 4; ++k4) {
        float xk[4] = {xr[k4].x, xr[k4].y, xr[k4].z, xr[k4].w};
        #pragma unroll
        for (int kk = 0; kk < 4; ++kk) {
            int k = k4 * 4 + kk;
            #pragma unroll
            for (int j = 0; j < 4; ++j) {
                float4 w = W4[k * 16 + strip * 4 + j];
                acc[j].x += xk[kk] * w.x; acc[j].y += xk[kk] * w.y;
                acc[j].z += xk[kk] * w.z; acc[j].w += xk[kk] * w.w;
            }
        }
    }
    float ps = 0.f, pd = 0.f;
    #pragma unroll
    for (int j = 0; j < 4; ++j) {
        int c = strip * 16 + j * 4;
        ps += acc[j].x * asl[c] + acc[j].y * asl[c + 1] + acc[j].z * asl[c + 2] + acc[j].w * asl[c + 3];
        pd += acc[j].x * adl[c] + acc[j].y * adl[c + 1] + acc[j].z * adl[c + 2] + acc[j].w * adl[c + 3];
    }
    ps += __shfl_xor(ps, 1);
    pd += __shfl_xor(pd, 1);
    if ((strip & 1) == 0) {
        int h = strip >> 1;
        a_srcv[n * 2 + h] = ps;
        a_dstv[n * 2 + h] = pd;
    }
    union { __half2 h[8]; int4 v[2]; } pk;
    #pragma unroll
    for (int j = 0; j < 4; ++j) {
        pk.h[2 * j]     = __floats2half2_rn(acc[j].x, acc[j].y);
        pk.h[2 * j + 1] = __floats2half2_rn(acc[j].z, acc[j].w);
    }
    int4* o = (int4*)(xs + (size_t)n * 64 + strip * 16);
    o[0] = pk.v[0];
    o[1] = pk.v[1];
}

__device__ __forceinline__ float2 h2f(int bits) {
    union { int i; __half2 h; } u; u.i = bits;
    return __half22float2(u.h);
}

// 16-lane group per node, TWO-PASS softmax (R13 structure), fp16 rec + fp16 xs.
template <int L>
__global__ __launch_bounds__(256) void node_agg_kernel(
    const int* __restrict__ rowptr, const int4* __restrict__ rec,
    const float* __restrict__ a_srcv, const float* __restrict__ a_dstv,
    const __half* __restrict__ xs, const float* __restrict__ b,
    float* __restrict__ out, int relu) {
    int nid = (blockIdx.x * 256 + threadIdx.x) >> 4;
    if (nid >= N_NODES) return;
    int lane = threadIdx.x & 63;
    int fl = lane & 15, h = fl >> 3;
    int gbase = lane & 48;                 // group's base lane in wave
    int beg = rowptr[nid], end = rowptr[nid + 1];
    float2 ad2 = ((const float2*)a_dstv)[nid];

    // ---- pass 1: per-lane online (m,den) + ae sums ----
    float m0 = -INFINITY, m1 = -INFINITY, d0 = 0.f, d1 = 0.f;
    float aes0 = 0.f, aes1 = 0.f;
    for (int j = beg + fl; j < end; j += 16) {
        int4 rv = rec[j];
        float2 aep = h2f((L == 0) ? rv.x : (L == 1) ? rv.y : rv.z);
        int s = rv.w;
        aes0 += aep.x; aes1 += aep.y;
        float2 as2 = ((const float2*)a_srcv)[s];
        float l0 = as2.x + ad2.x + aep.x;
        float l1 = as2.y + ad2.y + aep.y;
        l0 = (l0 > 0.f) ? l0 : 0.2f * l0;
        l1 = (l1 > 0.f) ? l1 : 0.2f * l1;
        float n0 = fmaxf(m0, l0);
        d0 = d0 * __expf(m0 - n0) + __expf(l0 - n0); m0 = n0;
        float n1 = fmaxf(m1, l1);
        d1 = d1 * __expf(m1 - n1) + __expf(l1 - n1); m1 = n1;
    }
    #pragma unroll
    for (int o = 8; o; o >>= 1) {          // 16-wide merge
        float mo0 = __shfl_xor(m0, o), do0 = __shfl_xor(d0, o);
        float mo1 = __shfl_xor(m1, o), do1 = __shfl_xor(d1, o);
        float n0 = fmaxf(m0, mo0);
        float ea0 = (m0 == n0) ? 1.f : __expf(m0 - n0);
        float eb0 = (mo0 == n0) ? 1.f : __expf(mo0 - n0);
        d0 = d0 * ea0 + do0 * eb0; m0 = n0;
        float n1 = fmaxf(m1, mo1);
        float ea1 = (m1 == n1) ? 1.f : __expf(m1 - n1);
        float eb1 = (mo1 == n1) ? 1.f : __expf(mo1 - n1);
        d1 = d1 * ea1 + do1 * eb1; m1 = n1;
        aes0 += __shfl_xor(aes0, o);
        aes1 += __shfl_xor(aes1, o);
    }
    // ---- self-loop fold ----
    int ne = end - beg;
    float invne = 1.f / fmaxf((float)ne, 1.f);
    float2 as2n = ((const float2*)a_srcv)[nid];
    float ls0 = as2n.x + ad2.x + aes0 * invne;
    float ls1 = as2n.y + ad2.y + aes1 * invne;
    ls0 = (ls0 > 0.f) ? ls0 : 0.2f * ls0;
    ls1 = (ls1 > 0.f) ? ls1 : 0.2f * ls1;
    float M0 = fmaxf(m0, ls0), M1 = fmaxf(m1, ls1);
    float sc0 = (m0 == M0) ? 1.f : __expf(m0 - M0);
    float sc1 = (m1 == M1) ? 1.f : __expf(m1 - M1);
    float exS0 = __expf(ls0 - M0), exS1 = __expf(ls1 - M1);
    float den0 = d0 * sc0 + exS0;
    float den1 = d1 * sc1 + exS1;

    // ---- pass 2: ex + quad-broadcast fp16 gathers ----
    float4 acc = make_float4(0.f, 0.f, 0.f, 0.f);
    for (int cb = beg; cb < end; cb += 16) {
        int j = cb + fl;
        float ex0 = 0.f, ex1 = 0.f;
        int s = 0;
        if (j < end) {
            int4 rv = rec[j];
            float2 aep = h2f((L == 0) ? rv.x : (L == 1) ? rv.y : rv.z);
            s = rv.w;
            float2 as2 = ((const float2*)a_srcv)[s];
            float l0 = as2.x + ad2.x + aep.x;
            float l1 = as2.y + ad2.y + aep.y;
            l0 = (l0 > 0.f) ? l0 : 0.2f * l0;
            l1 = (l1 > 0.f) ? l1 : 0.2f * l1;
            ex0 = __expf(l0 - M0);
            ex1 = __expf(l1 - M1);
        }
        int cnt = min(end - cb, 16);
        for (int t4 = 0; t4 < cnt; t4 += 4) {
            int tA = gbase + t4;
            float eA0 = __shfl(ex0, tA),     eA1 = __shfl(ex1, tA);     int sA = __shfl(s, tA);
            float eB0 = __shfl(ex0, tA + 1), eB1 = __shfl(ex1, tA + 1); int sB = __shfl(s, tA + 1);
            float eC0 = __shfl(ex0, tA + 2), eC1 = __shfl(ex1, tA + 2); int sC = __shfl(s, tA + 2);
            float eD0 = __shfl(ex0, tA + 3), eD1 = __shfl(ex1, tA + 3); int sD = __shfl(s, tA + 3);
            float eA = h ? eA1 : eA0, eB = h ? eB1 : eB0;
            float eC = h ? eC1 : eC0, eD = h ? eD1 : eD0;
            int2 xa = *(const int2*)(xs + (size_t)sA * 64 + fl * 4);
            int2 xb = *(const int2*)(xs + (size_t)sB * 64 + fl * 4);
            int2 xc = *(const int2*)(xs + (size_t)sC * 64 + fl * 4);
            int2 xd = *(const int2*)(xs + (size_t)sD * 64 + fl * 4);
            float2 a0 = h2f(xa.x), a1 = h2f(xa.y);
            float2 b0 = h2f(xb.x), b1 = h2f(xb.y);
            float2 c0 = h2f(xc.x), c1 = h2f(xc.y);
            float2 d0v = h2f(xd.x), d1v = h2f(xd.y);
            acc.x += eA * a0.x + eB * b0.x + eC * c0.x + eD * d0v.x;
            acc.y += eA * a0.y + eB * b0.y + eC * c0.y + eD * d0v.y;
            acc.z += eA * a1.x + eB * b1.x + eC * c1.x + eD * d1v.x;
            acc.w += eA * a1.y + eB * b1.y + eC * c1.y + eD * d1v.y;
        }
    }
    // self-loop contribution + epilogue
    float exSh = h ? exS1 : exS0;
    float den  = (h ? den1 : den0) + 1e-16f;
    int2 xv = *(const int2*)(xs + (size_t)nid * 64 + fl * 4);
    float2 s0 = h2f(xv.x), s1 = h2f(xv.y);
    float inv = 1.f / den;
    float4 b4 = ((const float4*)b)[fl];
    float4 v;
    v.x = (acc.x + exSh * s0.x) * inv + b4.x;
    v.y = (acc.y + exSh * s0.y) * inv + b4.y;
    v.z = (acc.z + exSh * s1.x) * inv + b4.z;
    v.w = (acc.w + exSh * s1.y) * inv + b4.w;
    if (relu) {
        v.x = fmaxf(v.x, 0.f); v.y = fmaxf(v.y, 0.f);
        v.z = fmaxf(v.z, 0.f); v.w = fmaxf(v.w, 0.f);
    }
    ((float4*)(out + (size_t)nid * 64))[fl] = v;
}

// ---------------- tail: pool + head fused (block g handles group g) ----------------

__global__ __launch_bounds__(256) void pool_head_kernel(
    const float* __restrict__ hfeat, const int* __restrict__ gstart,
    const float* __restrict__ Wl, const float* __restrict__ bl,
    float* __restrict__ out) {
    __shared__ float sm[4][64];
    __shared__ float pooledL[64];
    int g = blockIdx.x;
    int w = threadIdx.x >> 6, lane = threadIdx.x & 63;
    int beg = gstart[g], end = gstart[g + 1];
    float acc = 0.f;
    for (int n = beg + w; n < end; n += 4)
        acc += hfeat[(size_t)n * 64 + lane];
    sm[w][lane] = acc;
    __syncthreads();
    if (w == 0) {
        float v = sm[0][lane] + sm[1][lane] + sm[2][lane] + sm[3][lane];
        pooledL[lane] = v / fmaxf((float)(end - beg), 1.f);
    }
    __syncthreads();
    if (threadIdx.x < N_ACT) {
        int a = threadIdx.x;
        float s = bl[a];
        #pragma unroll
        for (int j = 0; j < 64; ++j) s += pooledL[j] * Wl[j * 8 + a];
        out[g * N_ACT + a] = tanhf(s);
    }
}

extern "C" void kernel_launch(void* const* d_in, const int* in_sizes, int n_in,
                              void* d_out, int out_size, void* d_ws, size_t ws_size,
                              hipStream_t stream) {
    const float* x    = (const float*)d_in[0];
    const int*   ei   = (const int*)d_in[1];
    const float* ea   = (const float*)d_in[2];
    const int*   batch= (const int*)d_in[3];
    const float* W[3]   = {(const float*)d_in[4],  (const float*)d_in[10], (const float*)d_in[16]};
    const float* We[3]  = {(const float*)d_in[5],  (const float*)d_in[11], (const float*)d_in[17]};
    const float* as_[3] = {(const float*)d_in[6],  (const float*)d_in[12], (const float*)d_in[18]};
    const float* ad_[3] = {(const float*)d_in[7],  (const float*)d_in[13], (const float*)d_in[19]};
    const float* ae_[3] = {(const float*)d_in[8],  (const float*)d_in[14], (const float*)d_in[20]};
    const float* b_[3]  = {(const float*)d_in[9],  (const float*)d_in[15], (const float*)d_in[21]};
    const float* Wlin = (const float*)d_in[22];
    const float* bl   = (const float*)d_in[23];
    float* out = (float*)d_out;

    float* ws = (float*)d_ws;
    size_t off = 0;
    float* A      = ws + off; off += (size_t)N_NODES * 64;   // layer io (fp32)
    __half* xs16  = (__half*)(ws + off); off += (size_t)N_NODES * 32;  // fp16 xs
    int4* rec     = (int4*)(ws + off); off += (size_t)N_EDGES * 4;     // 16B records
    float* a_srcv = ws + off; off += N_NODES * 2;
    float* a_dstv = ws + off; off += N_NODES * 2;
    float* weff   = ws + off; off += 32;
    int* rowptr = (int*)(ws + off); off += N_NODES + 1;
    int* hist   = (int*)(ws + off); off += N_NODES;          // hist+cur contiguous
    int* cur    = (int*)(ws + off); off += N_NODES;
    int* gstart = (int*)(ws + off); off += N_G + 1;
    int* bsum   = (int*)(ws + off); off += SNB;

    // ---- once-per-call setup ----
    hipMemsetAsync(hist, 0, 2 * N_NODES * sizeof(int), stream);   // hist + cur
    setup_kernel<<<1 + (N_EDGES + 255) / 256, 256, 0, stream>>>(
        ei, batch, We[0], ae_[0], We[1], ae_[1], We[2], ae_[2], weff, gstart, hist);
    scan_bsum_kernel<<<SNB, SBLK, 0, stream>>>(hist, bsum);
    scan_rowptr_kernel<<<SNB, SBLK, 0, stream>>>(hist, bsum, rowptr);
    scatter_kernel<<<(N_EH + 255) / 256, 256, 0, stream>>>(ei, ea, weff, rowptr, cur, rec);

    const int NB = (N_NODES * 16 + 255) / 256;   // 16 nodes per block
    const int FB = (N_NODES + 63) / 64;
    for (int l = 0; l < 3; ++l) {
        if (l == 0)
            feat_kernel<32><<<FB, 256, 0, stream>>>(x, W[0], as_[0], ad_[0], xs16, a_srcv, a_dstv);
        else
            feat_kernel<64><<<FB, 256, 0, stream>>>(A, W[l], as_[l], ad_[l], xs16, a_srcv, a_dstv);
        if (l == 0)
            node_agg_kernel<0><<<NB, 256, 0, stream>>>(rowptr, rec, a_srcv, a_dstv, xs16, b_[0], A, 1);
        else if (l == 1)
            node_agg_kernel<1><<<NB, 256, 0, stream>>>(rowptr, rec, a_srcv, a_dstv, xs16, b_[1], A, 1);
        else
            node_agg_kernel<2><<<NB, 256, 0, stream>>>(rowptr, rec, a_srcv, a_dstv, xs16, b_[2], A, 0);
    }
    pool_head_kernel<<<N_G, 256, 0, stream>>>(A, gstart, Wlin, bl, out);
}